// Round 12
// baseline (732.836 us; speedup 1.0000x reference)
//
#include <hip/hip_runtime.h>
#include <hip/hip_bf16.h>

// MoEFSCIL: B=16, H=W=16, L=256, DIM=768, NH=8, HD=96, NEXP=8, TOPK=2.
// fp32 in/out. ALL GEMMs bf16 MFMA with global_load_lds(16B) staging. Scan at
// r7 state (155us structural floor, control). r12: dispatch-count reduction
// round 2 (16 -> 13): gate path collapsed to ONE kernel (k2 GEMM computed
// in-block, 16x redundant = 150 MFLOP, gacc+atomics eliminated); mk_out
// absorbed into lnfin via last-block counter (eo re-read through atomicAdd(p,0)
// = cross-XCD-safe); counter zeroed in mk_dbl.

#define LTOK 256
#define DIMC 768

typedef unsigned short ushortt;
typedef __attribute__((ext_vector_type(8))) short bf16x8;
typedef __attribute__((ext_vector_type(4))) float f32x4;

#define LOG2E 1.44269504f
#define LN2   0.69314718f

__device__ __forceinline__ void gld16(const ushortt* gp, ushortt* lp) {
  __builtin_amdgcn_global_load_lds(
      (const __attribute__((address_space(1))) void*)gp,
      (__attribute__((address_space(3))) void*)lp, 16, 0, 0);
}

__device__ __forceinline__ float fexp2(float x) { return __builtin_amdgcn_exp2f(x); }
__device__ __forceinline__ float flog2(float x) { return __builtin_amdgcn_logf(x); }

__device__ __forceinline__ ushortt f2b(float f) {
  union { float f; unsigned u; } c; c.f = f;
  unsigned r = (c.u + 0x7FFFu + ((c.u >> 16) & 1u)) >> 16;
  return (ushortt)r;
}

// ---------------------------------------------------------------------------
// Fused 4-tensor fp32->bf16 cast (x, sa_in_w, sa_out_w, ca_in_w[:768] rows).
// ---------------------------------------------------------------------------
__global__ __launch_bounds__(256) void mk_mcast4(
    const float* __restrict__ s0, ushortt* __restrict__ d0,
    const float* __restrict__ s1, ushortt* __restrict__ d1,
    const float* __restrict__ s2, ushortt* __restrict__ d2,
    const float* __restrict__ s3, ushortt* __restrict__ d3)
{
  long g = (long)blockIdx.x * 256 + threadIdx.x;   // float4 chunk id
  const float* s; ushortt* dst; long o;
  if (g < 786432)       { s = s0; dst = d0; o = g; }
  else if (g < 1228800) { s = s1; dst = d1; o = g - 786432; }
  else if (g < 1376256) { s = s2; dst = d2; o = g - 1228800; }
  else                  { s = s3; dst = d3; o = g - 1376256; }
  o <<= 2;
  float4 v = *(const float4*)(s + o);
  ushort4 w;
  w.x = f2b(v.x); w.y = f2b(v.y); w.z = f2b(v.z); w.w = f2b(v.w);
  *(ushort4*)(dst + o) = w;
}

__global__ __launch_bounds__(256) void mk_cast(const float* __restrict__ in,
                                               ushortt* __restrict__ outp, long n)
{
  long i = ((long)blockIdx.x * 256 + threadIdx.x) * 4;
  if (i + 3 < n) {
    float4 v = *(const float4*)(in + i);
    ushort4 o;
    o.x = f2b(v.x); o.y = f2b(v.y); o.z = f2b(v.z); o.w = f2b(v.w);
    *(ushort4*)(outp + i) = o;
  }
}

// ---------------------------------------------------------------------------
// bf16 MFMA GEMM: C[z] = A[z](M,K) @ B[z](N,K)^T + bias.
// Staging: global_load_lds width=16, linear LDS [128][32] ushort with XOR
// swizzle phys_grp = log_grp ^ ((row>>1)&3) (r9, verified).
// ---------------------------------------------------------------------------
__global__ __launch_bounds__(256) void mk_mfma(
    const ushortt* __restrict__ A, const ushortt* __restrict__ B,
    const float* __restrict__ bias, void* __restrict__ C,
    int K, int lda, int ldb, int ldc,
    int zdiv, long sA1, long sA2, long sB1, long sB2, long sC1, long sC2,
    long sBias,
    const int* __restrict__ pairExp, int tilesN,
    int outBf, int splitN, void* __restrict__ C2, int ldc2, int outBf2, int c2vt)
{
  int z = blockIdx.y;
  long aoff, boff, coff, biasoff = 0;
  if (pairExp) {
    int e = pairExp[z];
    aoff = (long)(z >> 1) * sA1; boff = (long)e * sB1;
    coff = (long)z * sC1; biasoff = (long)e * sBias;
  } else {
    int z1 = z / zdiv, z2 = z - z1 * zdiv;
    aoff = (long)z1 * sA1 + (long)z2 * sA2;
    boff = (long)z1 * sB1 + (long)z2 * sB2;
    coff = (long)z1 * sC1 + (long)z2 * sC2;
  }
  int tile = blockIdx.x;
  int tm = tile / tilesN, tn = tile - tm * tilesN;
  long m0 = (long)tm << 7, n0 = (long)tn << 7;

  __shared__ ushortt As[128 * 32];
  __shared__ ushortt Bs[128 * 32];

  int tid = threadIdx.x;
  int lane = tid & 63, wvi = tid >> 6;
  int wr = wvi >> 1, wc = wvi & 1;
  int lm = lane & 15, lg = lane >> 4;

  f32x4 zero4 = {0.f, 0.f, 0.f, 0.f};
  f32x4 acc[4][4];
#pragma unroll
  for (int i = 0; i < 4; i++)
#pragma unroll
    for (int j = 0; j < 4; j++) acc[i][j] = zero4;

  const ushortt* Ab = A + aoff;
  const ushortt* Bb = B + boff;

  int srow = (wvi << 5) + (lane >> 2);
  int sglog = ((lane & 3) ^ ((lane >> 3) & 3)) << 3;   // ushort offset
  const ushortt* agp = Ab + (m0 + srow) * lda + sglog;
  const ushortt* bgp = Bb + (n0 + srow) * ldb + sglog;
  ushortt* al0 = &As[(wvi << 5) << 5];
  ushortt* al1 = &As[((wvi << 5) + 16) << 5];
  ushortt* bl0 = &Bs[(wvi << 5) << 5];
  ushortt* bl1 = &Bs[((wvi << 5) + 16) << 5];

  int pswz = (lg ^ ((lm >> 1) & 3)) << 3;
  const ushortt* afp[4];
  const ushortt* bfp[4];
#pragma unroll
  for (int i = 0; i < 4; i++) {
    afp[i] = &As[((wr * 64 + i * 16 + lm) << 5) + pswz];
    bfp[i] = &Bs[((wc * 64 + i * 16 + lm) << 5) + pswz];
  }

  for (int k0 = 0; k0 < K; k0 += 32) {
    gld16(agp, al0);
    gld16(agp + 16 * lda, al1);
    gld16(bgp, bl0);
    gld16(bgp + 16 * ldb, bl1);
    agp += 32; bgp += 32;
    __syncthreads();
    bf16x8 af[4], bfr[4];
#pragma unroll
    for (int i = 0; i < 4; i++) {
      af[i] = *(const bf16x8*)afp[i];
      bfr[i] = *(const bf16x8*)bfp[i];
    }
#pragma unroll
    for (int i = 0; i < 4; i++)
#pragma unroll
      for (int j = 0; j < 4; j++)
        acc[i][j] = __builtin_amdgcn_mfma_f32_16x16x32_bf16(af[i], bfr[j], acc[i][j], 0, 0, 0);
    __syncthreads();
  }

#pragma unroll
  for (int mt = 0; mt < 4; mt++) {
#pragma unroll
    for (int nt = 0; nt < 4; nt++) {
      long grow = m0 + wr * 64 + mt * 16 + lg * 4;
      long gcol = n0 + wc * 64 + nt * 16 + lm;
      float bv = bias ? bias[biasoff + gcol] : 0.f;
      if ((int)gcol < splitN) {
#pragma unroll
        for (int r = 0; r < 4; r++) {
          float v = acc[mt][nt][r] + bv;
          long idx = coff + (grow + r) * ldc + gcol;
          if (outBf) ((ushortt*)C)[idx] = f2b(v);
          else ((float*)C)[idx] = v;
        }
      } else if (c2vt) {
        int cc = (int)gcol - splitN;            // 0..767
        int hh = cc / 96, jj = cc - hh * 96;
#pragma unroll
        for (int r = 0; r < 4; r++) {
          float v = acc[mt][nt][r] + bv;
          long gr = grow + r;
          long b = gr >> 8, t = gr & 255;
          long idx = (((b * 8 + hh) * 128 + jj) << 8) + t;
          ((ushortt*)C2)[idx] = f2b(v);
        }
      } else {
        long col = gcol - splitN;
#pragma unroll
        for (int r = 0; r < 4; r++) {
          float v = acc[mt][nt][r] + bv;
          long idx = coff + (grow + r) * ldc2 + col;
          if (outBf2) ((ushortt*)C2)[idx] = f2b(v);
          else ((float*)C2)[idx] = v;
        }
      }
    }
  }
}

// ---------------------------------------------------------------------------
// Fused softmax + att@V (r11, verified).
// ---------------------------------------------------------------------------
__global__ __launch_bounds__(256) void mk_attv(const float* __restrict__ scores,
                                               const ushortt* __restrict__ vt,
                                               ushortt* __restrict__ ctxa)
{
  __shared__ ushortt Vs[96 * 264];
  __shared__ __attribute__((aligned(16))) ushortt As[128 * 40];
  int z = blockIdx.y, half = blockIdx.x;
  int t = threadIdx.x;
  const float* srow = scores + (long)z * 65536 + (long)half * 128 * 256;
  const ushortt* vb = vt + (long)z * 32768;

  for (int it = 0; it < 12; it++) {
    int cch = it * 256 + t;
    int j = cch >> 5, q = cch & 31;
    *(uint4*)&Vs[j * 264 + q * 8] = *(const uint4*)(vb + j * 256 + q * 8);
  }

  int r = t >> 1, hf = t & 1;
  const float* sp = srow + (long)r * 256 + hf * 128;
  const float sl = 0.10206207261596577f * LOG2E;
  float m = -3.4e38f;
  for (int j = 0; j < 128; j += 4) {
    float4 v = *(const float4*)(sp + j);
    m = fmaxf(m, fmaxf(fmaxf(v.x, v.y), fmaxf(v.z, v.w)));
  }
  m = fmaxf(m, __shfl_xor(m, 1, 64));
  float s = 0.f;
  for (int j = 0; j < 128; j += 4) {
    float4 v = *(const float4*)(sp + j);
    s += fexp2(sl * (v.x - m)) + fexp2(sl * (v.y - m)) +
         fexp2(sl * (v.z - m)) + fexp2(sl * (v.w - m));
  }
  s += __shfl_xor(s, 1, 64);
  float rinv = 1.f / s;

  int lane = t & 63, w = t >> 6;
  int lm = lane & 15, lg = lane >> 4;
  f32x4 zero4 = {0.f, 0.f, 0.f, 0.f};
  f32x4 acc[2][6];
#pragma unroll
  for (int i = 0; i < 2; i++)
#pragma unroll
    for (int j = 0; j < 6; j++) acc[i][j] = zero4;

  const float* stp = srow + (long)(t >> 1) * 256 + (t & 1) * 16;
  ushortt* adst = &As[(t >> 1) * 40 + (t & 1) * 16];

  for (int k0 = 0; k0 < 256; k0 += 32) {
    float4 a0 = *(const float4*)(stp + k0);
    float4 a1 = *(const float4*)(stp + k0 + 4);
    float4 a2 = *(const float4*)(stp + k0 + 8);
    float4 a3 = *(const float4*)(stp + k0 + 12);
    ushortt pk[16];
    pk[0]  = f2b(fexp2(sl * (a0.x - m)) * rinv);
    pk[1]  = f2b(fexp2(sl * (a0.y - m)) * rinv);
    pk[2]  = f2b(fexp2(sl * (a0.z - m)) * rinv);
    pk[3]  = f2b(fexp2(sl * (a0.w - m)) * rinv);
    pk[4]  = f2b(fexp2(sl * (a1.x - m)) * rinv);
    pk[5]  = f2b(fexp2(sl * (a1.y - m)) * rinv);
    pk[6]  = f2b(fexp2(sl * (a1.z - m)) * rinv);
    pk[7]  = f2b(fexp2(sl * (a1.w - m)) * rinv);
    pk[8]  = f2b(fexp2(sl * (a2.x - m)) * rinv);
    pk[9]  = f2b(fexp2(sl * (a2.y - m)) * rinv);
    pk[10] = f2b(fexp2(sl * (a2.z - m)) * rinv);
    pk[11] = f2b(fexp2(sl * (a2.w - m)) * rinv);
    pk[12] = f2b(fexp2(sl * (a3.x - m)) * rinv);
    pk[13] = f2b(fexp2(sl * (a3.y - m)) * rinv);
    pk[14] = f2b(fexp2(sl * (a3.z - m)) * rinv);
    pk[15] = f2b(fexp2(sl * (a3.w - m)) * rinv);
    *(uint4*)adst = *(uint4*)&pk[0];
    *(uint4*)(adst + 8) = *(uint4*)&pk[8];
    __syncthreads();
    bf16x8 af[2], bfr[6];
#pragma unroll
    for (int i = 0; i < 2; i++)
      af[i] = *(const bf16x8*)&As[(w * 32 + i * 16 + lm) * 40 + lg * 8];
#pragma unroll
    for (int j = 0; j < 6; j++)
      bfr[j] = *(const bf16x8*)&Vs[(j * 16 + lm) * 264 + k0 + lg * 8];
#pragma unroll
    for (int i = 0; i < 2; i++)
#pragma unroll
      for (int j = 0; j < 6; j++)
        acc[i][j] = __builtin_amdgcn_mfma_f32_16x16x32_bf16(af[i], bfr[j], acc[i][j], 0, 0, 0);
    __syncthreads();
  }

  int b = z >> 3, h = z & 7;
#pragma unroll
  for (int i = 0; i < 2; i++) {
#pragma unroll
    for (int j = 0; j < 6; j++) {
      int tok = half * 128 + w * 32 + i * 16 + lg * 4;
      int col = j * 16 + lm;
#pragma unroll
      for (int rr2 = 0; rr2 < 4; rr2++) {
        ctxa[((long)(b * 256 + tok + rr2)) * 768 + h * 96 + col] = f2b(acc[i][j][rr2]);
      }
    }
  }
}

// ---------------------------------------------------------------------------
// Fused gate path: 16 blocks (one per batch b). Replaces k2 GEMM + gates +
// gatetop. Phase 1: k2p[e][h*100+j] computed in-block (eq in LDS; k2p reads
// in phase 2 are all-lane-uniform -> broadcast). Phase 2: thread = token,
// per-head softmax over experts, accumulate. Phase 3: shuffle+LDS reduce,
// thread 0 does softmax/top-2/sigmoid -> pe/pw.
// ---------------------------------------------------------------------------
__global__ __launch_bounds__(256) void mk_gates16(
    const float* __restrict__ q2,
    const float* __restrict__ eq,
    const float* __restrict__ caw2,
    const float* __restrict__ cab2,
    int* __restrict__ pe, float* __restrict__ pw)
{
  __shared__ float eqS[8 * 768];
  __shared__ float k2p[8 * 808];
  __shared__ float red2[4][8];
  int b = blockIdx.x;
  int tid = threadIdx.x;
  for (int i = tid; i < 1536; i += 256)
    ((float4*)eqS)[i] = ((const float4*)eq)[i];
  __syncthreads();
  // k2p[e][h*100+j] = cab2[n] + eq[e] . caw2[n],  n = h*96 + j
#pragma unroll 1
  for (int nc = 0; nc < 3; nc++) {
    int n = nc * 256 + tid;
    const float* wrow = caw2 + (long)n * 768;
    float cb = cab2[n];
    float acc[8];
#pragma unroll
    for (int e = 0; e < 8; e++) acc[e] = cb;
#pragma unroll 1
    for (int k = 0; k < 768; k += 4) {
      float4 wv = *(const float4*)(wrow + k);
#pragma unroll
      for (int e = 0; e < 8; e++) {
        float4 ev = *(const float4*)&eqS[e * 768 + k];
        acc[e] += ev.x * wv.x + ev.y * wv.y + ev.z * wv.z + ev.w * wv.w;
      }
    }
    int h = n / 96, j = n - h * 96;
#pragma unroll
    for (int e = 0; e < 8; e++) k2p[e * 808 + h * 100 + j] = acc[e];
  }
  __syncthreads();

  const float scale = 0.10206207261596577f;
  const float* qrow = q2 + ((long)b * LTOK + tid) * DIMC;
  float acc8[8];
#pragma unroll
  for (int e = 0; e < 8; e++) acc8[e] = 0.f;
#pragma unroll 1
  for (int h = 0; h < 8; h++) {
    float s8[8];
#pragma unroll
    for (int e = 0; e < 8; e++) s8[e] = 0.f;
    const float* qh = qrow + h * 96;
#pragma unroll 1
    for (int j = 0; j < 96; j += 4) {
      float4 qv = *(const float4*)(qh + j);
#pragma unroll
      for (int e = 0; e < 8; e++) {
        float4 kv = *(const float4*)&k2p[e * 808 + h * 100 + j];
        s8[e] += qv.x * kv.x + qv.y * kv.y + qv.z * kv.z + qv.w * kv.w;
      }
    }
    float mx = s8[0] * scale;
#pragma unroll
    for (int e = 1; e < 8; e++) mx = fmaxf(mx, s8[e] * scale);
    float se = 0.f, ex8[8];
#pragma unroll
    for (int e = 0; e < 8; e++) { ex8[e] = fexp2((s8[e] * scale - mx) * LOG2E); se += ex8[e]; }
    float rr = 1.f / se;
#pragma unroll
    for (int e = 0; e < 8; e++) acc8[e] += ex8[e] * rr;
  }
#pragma unroll
  for (int e = 0; e < 8; e++)
#pragma unroll
    for (int o = 32; o; o >>= 1) acc8[e] += __shfl_xor(acc8[e], o, 64);
  int wid = tid >> 6, lane = tid & 63;
  if (lane == 0) {
#pragma unroll
    for (int e = 0; e < 8; e++) red2[wid][e] = acc8[e];
  }
  __syncthreads();
  if (tid == 0) {
    float g[8];
    for (int e = 0; e < 8; e++)
      g[e] = (red2[0][e] + red2[1][e] + red2[2][e] + red2[3][e]) * (1.f / (8.f * 256.f));
    float mx = g[0];
    for (int e = 1; e < 8; e++) mx = fmaxf(mx, g[e]);
    float se = 0.f;
    for (int e = 0; e < 8; e++) { g[e] = expf(g[e] - mx); se += g[e]; }
    for (int e = 0; e < 8; e++) g[e] /= se;
    int i0 = 0;
    for (int e = 1; e < 8; e++) if (g[e] > g[i0]) i0 = e;
    int i1 = (i0 == 0) ? 1 : 0;
    for (int e = 0; e < 8; e++) if (e != i0 && g[e] > g[i1]) i1 = e;
    float w0 = 1.f / (1.f + expf(g[i1] - g[i0]));
    pe[2 * b] = i0; pe[2 * b + 1] = i1;
    pw[2 * b] = w0; pw[2 * b + 1] = 1.f - w0;
  }
}

// ---------------------------------------------------------------------------
// Depthwise conv + SiLU: 8 tokens/block, weights hoisted to registers.
// ---------------------------------------------------------------------------
__global__ __launch_bounds__(768) void mk_conv(const float* __restrict__ xzx,
                                               const float* __restrict__ cw,
                                               const float* __restrict__ cb,
                                               const int* __restrict__ pe,
                                               float* __restrict__ xc)
{
  int blk = blockIdx.x;
  int p = blk >> 5, tg = blk & 31;
  int e = pe[p];
  int c = threadIdx.x;
  const float* wp = cw + ((long)e * DIMC + c) * 9;
  float w9[9];
#pragma unroll
  for (int i = 0; i < 9; i++) w9[i] = wp[i];
  float bias = cb[e * DIMC + c];
  const float* xb = xzx + (long)p * LTOK * DIMC + c;
#pragma unroll
  for (int i = 0; i < 8; i++) {
    int t = tg * 8 + i;
    int h = t >> 4, w = t & 15;
    float acc = bias;
#pragma unroll
    for (int dh = 0; dh < 3; dh++) {
      int hh = h + dh - 1;
      if (hh < 0 || hh > 15) continue;
#pragma unroll
      for (int dw = 0; dw < 3; dw++) {
        int ww = w + dw - 1;
        if (ww < 0 || ww > 15) continue;
        acc += xb[(long)(hh * 16 + ww) * DIMC] * w9[dh * 3 + dw];
      }
    }
    xc[((long)p * LTOK + t) * DIMC + c] = acc / (1.f + fexp2(-acc * LOG2E));
  }
}

__device__ __forceinline__ int tmap(int dir, int s) {
  if (dir == 0) return s;
  if (dir == 1) return 255 - s;
  if (dir == 2) return ((s & 15) << 4) | (s >> 4);
  int u = 255 - s;
  return ((u & 15) << 4) | (u >> 4);
}

// ---------------------------------------------------------------------------
// dbl: wave-per-token. Output dblm2[p] per-dir traversal, bank-staggered.
// Zeros eo (blocks 0..95) and the lnfin completion counter (block 96).
// ---------------------------------------------------------------------------
__global__ __launch_bounds__(256) void mk_dbl(const float* __restrict__ xc,
                                              const float* __restrict__ xproj,
                                              const int* __restrict__ pe,
                                              float* __restrict__ dblm,
                                              float* __restrict__ eo,
                                              int* __restrict__ cnt)
{
  if (blockIdx.x < 96) eo[blockIdx.x * 256 + threadIdx.x] = 0.f;
  if (blockIdx.x == 96 && threadIdx.x == 0) *cnt = 0;
  int p = blockIdx.x >> 6;
  int tq = blockIdx.x & 63;
  int wid = threadIdx.x >> 6, lane = threadIdx.x & 63;
  int m = tq * 4 + wid;
  int e = pe[p];
  const float* xr = xc + ((long)p * LTOK + m) * DIMC;
  const float* wb = xproj + (long)e * 24 * DIMC;
  float4 xv[3];
#pragma unroll
  for (int j = 0; j < 3; j++) xv[j] = *(const float4*)(xr + j * 256 + lane * 4);
  float acc[24];
#pragma unroll
  for (int r = 0; r < 24; r++) {
    const float* wr = wb + r * DIMC;
    float s = 0.f;
#pragma unroll
    for (int j = 0; j < 3; j++) {
      float4 wv = *(const float4*)(wr + j * 256 + lane * 4);
      s += xv[j].x * wv.x + xv[j].y * wv.y + xv[j].z * wv.z + xv[j].w * wv.w;
    }
    acc[r] = s;
  }
#pragma unroll
  for (int r = 0; r < 24; r++)
#pragma unroll
    for (int o = 32; o; o >>= 1) acc[r] += __shfl_xor(acc[r], o, 64);
  if (lane == 0) {
    float* o = dblm + (long)p * 6144;
#pragma unroll
    for (int dd = 0; dd < 4; dd++) {
      int s = tmap(dd, m);
      int ss = ((s & 31) << 3) | (s >> 5);
      float* oa = o + dd * 1024 + ss * 4;
      oa[0] = acc[dd * 6 + 0]; oa[1] = acc[dd * 6 + 1];
      oa[2] = acc[dd * 6 + 2]; oa[3] = acc[dd * 6 + 3];
      float* ob = o + 4096 + dd * 512 + ss * 2;
      ob[0] = acc[dd * 6 + 4]; ob[1] = acc[dd * 6 + 5];
    }
  }
}

// ---------------------------------------------------------------------------
// Fused segmented scan (r7 state: 155us structural floor, kept as control).
// ---------------------------------------------------------------------------
__global__ __launch_bounds__(512, 6) void mk_scan(const float* __restrict__ xc,
                                               const float* __restrict__ dblm,
                                               const float* __restrict__ dtw,
                                               const float* __restrict__ dtb,
                                               const float* __restrict__ Alog,
                                               const float* __restrict__ Dp,
                                               const int* __restrict__ pe,
                                               float* __restrict__ yac)
{
  __shared__ __attribute__((aligned(16))) float dtS[4096];   // [dir][ss][4]
  __shared__ __attribute__((aligned(16))) float bcS[2048];   // [dir][ss][2]
  __shared__ float yS[256 * 18];
  __shared__ float ahS[32][16][2];
  __shared__ float dsum[16];
  int blk = blockIdx.x;
  int p = blk / 48, cg = blk - p * 48;
  int c0 = cg << 4;
  int e = pe[p];
  int tid = threadIdx.x;
  {
    const float4* src = (const float4*)(dblm + (long)p * 6144);
    float4* dA = (float4*)dtS;
    for (int i = tid; i < 1024; i += 512) dA[i] = src[i];
    if (tid < 512) ((float4*)bcS)[tid] = src[1024 + tid];
  }
  for (int i = tid; i < 256 * 18; i += 512) yS[i] = 0.f;
  if (tid < 16) {
    float s = 0.f;
#pragma unroll
    for (int dd = 0; dd < 4; dd++) s += Dp[(long)(e * 4 + dd) * DIMC + c0 + tid];
    dsum[tid] = s;
  }
  __syncthreads();

  int c = tid & 15;
  int rr = tid >> 4;
  int seg = rr & 7;
  int dir = rr >> 3;
  int d = c0 + c;
  const float* xcp = xc + (long)p * LTOK * DIMC + d;
  long pb = (long)(e * 4 + dir) * DIMC + d;
  float4 wv = *(const float4*)(dtw + pb * 4);
  wv.x *= LOG2E; wv.y *= LOG2E; wv.z *= LOG2E; wv.w *= LOG2E;
  float bdt = dtb[pb] * LOG2E;
  float Ad = -fexp2(Alog[pb] * LOG2E);
  int t0 = seg << 5;
  const float* dtP = &dtS[(dir << 10) + (seg << 2)];
  const float* bcP = &bcS[(dir << 9) + (seg << 1)];

  float h = 0.f, ap = 1.f;
#pragma unroll 1
  for (int tb = 0; tb < 32; tb += 4) {
#pragma unroll
    for (int u = 0; u < 4; u++) {
      int i = tb + u;
      float4 dv = *(const float4*)(dtP + i * 32);
      float2 bc = *(const float2*)(bcP + i * 16);
      int mm = tmap(dir, t0 + i);
      float xv = xcp[(long)mm * DIMC];
      float xl = wv.x * dv.x + wv.y * dv.y + wv.z * dv.z + wv.w * dv.w + bdt;
      float te = fexp2(xl);
      float g = flog2(1.f + te);
      g = (xl > 86.f) ? xl : g;
      float de = fexp2(g * Ad);
      h = de * h + (g * LN2 * bc.x) * xv;
      ap *= de;
    }
    __builtin_amdgcn_sched_barrier(0);
  }
  ahS[rr][c][0] = ap;
  ahS[rr][c][1] = h;
  __syncthreads();

  float hh = 0.f;
  {
    int base = dir << 3;
    float av[8], hv[8];
#pragma unroll
    for (int j = 0; j < 8; j++) {
      av[j] = ahS[base + j][c][0];
      hv[j] = ahS[base + j][c][1];
    }
#pragma unroll
    for (int j = 0; j < 7; j++)
      if (j < seg) hh = av[j] * hh + hv[j];
  }

#pragma unroll 1
  for (int tb = 0; tb < 32; tb += 4) {
#pragma unroll
    for (int u = 0; u < 4; u++) {
      int i = tb + u;
      float4 dv = *(const float4*)(dtP + i * 32);
      float2 bc = *(const float2*)(bcP + i * 16);
      int mm = tmap(dir, t0 + i);
      float xv = xcp[(long)mm * DIMC];
      float xl = wv.x * dv.x + wv.y * dv.y + wv.z * dv.z + wv.w * dv.w + bdt;
      float te = fexp2(xl);
      float g = flog2(1.f + te);
      g = (xl > 86.f) ? xl : g;
      float de = fexp2(g * Ad);
      hh = de * hh + (g * LN2 * bc.x) * xv;
      atomicAdd(&yS[mm * 18 + c + (((mm >> 5) & 1) << 1)], hh * bc.y);
    }
    __builtin_amdgcn_sched_barrier(0);
  }
  __syncthreads();

  const float* xcb = xc + (long)p * LTOK * DIMC + c0;
  float* yp = yac + (long)p * LTOK * DIMC + c0;
  for (int i = tid; i < 4096; i += 512) {
    int t = i >> 4, cz = i & 15;
    yp[(long)t * DIMC + cz] = yS[t * 18 + cz + (((t >> 5) & 1) << 1)] +
        xcb[(long)t * DIMC + cz] * dsum[cz];
  }
}

// ---------------------------------------------------------------------------
// LN + silu(z) + token partial-mean + (last block) weighted top-2 combine.
// 512 blocks; completion counter (pre-zeroed in mk_dbl); last block re-reads
// eo via atomicAdd(p,0) (cross-XCD-safe) and writes out.
// ---------------------------------------------------------------------------
__global__ __launch_bounds__(256) void mk_lnfin(const float* __restrict__ yac,
                                                const float* __restrict__ xzz,
                                                const float* __restrict__ lns,
                                                const float* __restrict__ lnb,
                                                const int* __restrict__ pe,
                                                float* __restrict__ eo,
                                                const float* __restrict__ pw,
                                                float* __restrict__ out,
                                                int* __restrict__ cnt)
{
  int blk = blockIdx.x;
  int p = blk >> 4, ts = blk & 15;
  int e = pe[p];
  int tid = threadIdx.x;
  int wid = tid >> 6, lane = tid & 63;
  float ls[12], lb[12], acc[12];
#pragma unroll
  for (int i = 0; i < 12; i++) {
    int d = i * 64 + lane;
    ls[i] = lns[e * DIMC + d];
    lb[i] = lnb[e * DIMC + d];
    acc[i] = 0.f;
  }
#pragma unroll
  for (int tt = 0; tt < 4; tt++) {
    int t = ts * 16 + wid * 4 + tt;
    const float* yr = yac + ((long)p * LTOK + t) * DIMC;
    const float* zr = xzz + ((long)p * LTOK + t) * DIMC;
    float v[12];
    float s = 0.f;
#pragma unroll
    for (int i = 0; i < 12; i++) { v[i] = yr[i * 64 + lane]; s += v[i]; }
#pragma unroll
    for (int o = 32; o; o >>= 1) s += __shfl_xor(s, o, 64);
    float mu = s * (1.f / 768.f);
    float sq = 0.f;
#pragma unroll
    for (int i = 0; i < 12; i++) { float dlt = v[i] - mu; sq += dlt * dlt; }
#pragma unroll
    for (int o = 32; o; o >>= 1) sq += __shfl_xor(sq, o, 64);
    float rs = rsqrtf(sq * (1.f / 768.f) + 1e-5f);
#pragma unroll
    for (int i = 0; i < 12; i++) {
      float y = (v[i] - mu) * rs * ls[i] + lb[i];
      float z = zr[i * 64 + lane];
      y *= z / (1.f + fexp2(-z * LOG2E));
      acc[i] += y;
    }
  }
  __shared__ float sacc[768];
  for (int j = tid; j < 768; j += 256) sacc[j] = 0.f;
  __syncthreads();
#pragma unroll
  for (int i = 0; i < 12; i++) atomicAdd(&sacc[i * 64 + lane], acc[i]);
  __syncthreads();
  for (int j = tid; j < 768; j += 256) atomicAdd(&eo[(long)p * DIMC + j], sacc[j]);

  // completion + tail combine in the last block
  __threadfence();
  __syncthreads();
  __shared__ int isLast;
  if (tid == 0) isLast = (atomicAdd(cnt, 1) == 511) ? 1 : 0;
  __syncthreads();
  if (isLast) {
    for (int i = tid; i < 12288; i += 256) {
      int b2 = i / 768, d = i - b2 * 768;
      float v0 = atomicAdd(&eo[(long)(2 * b2) * DIMC + d], 0.f);
      float v1 = atomicAdd(&eo[(long)(2 * b2 + 1) * DIMC + d], 0.f);
      out[i] = (pw[2 * b2] * v0 + pw[2 * b2 + 1] * v1) * (1.f / 256.f);
    }
  }
}

// ---------------------------------------------------------------------------
extern "C" void kernel_launch(void* const* d_in, const int* in_sizes, int n_in,
                              void* d_out, int out_size, void* d_ws, size_t ws_size,
                              hipStream_t stream)
{
  const float* x        = (const float*)d_in[0];
  const float* sa_in_w  = (const float*)d_in[1];
  const float* sa_in_b  = (const float*)d_in[2];
  const float* sa_out_w = (const float*)d_in[3];
  const float* sa_out_b = (const float*)d_in[4];
  const float* ca_in_w  = (const float*)d_in[5];
  const float* ca_in_b  = (const float*)d_in[6];
  const float* eq       = (const float*)d_in[7];
  const float* e_in_w   = (const float*)d_in[8];
  const float* e_in_b   = (const float*)d_in[9];
  const float* e_conv_w = (const float*)d_in[10];
  const float* e_conv_b = (const float*)d_in[11];
  const float* e_xproj  = (const float*)d_in[12];
  const float* e_dtw    = (const float*)d_in[13];
  const float* e_dtb    = (const float*)d_in[14];
  const float* e_Alog   = (const float*)d_in[15];
  const float* e_D      = (const float*)d_in[16];
  const float* e_lns    = (const float*)d_in[17];
  const float* e_lnb    = (const float*)d_in[18];
  float* out = (float*)d_out;

  float* ws = (float*)d_ws;
  // ---- attention phase (float offsets) ----
  ushortt* qk_b   = (ushortt*)(ws + 0);          // 4096x1536 bf16  [0 .. 3,145,728)
  float*   scores = ws + 6291456;                // [6,291,456 .. 14,680,064)
  ushortt* ctxa_b = (ushortt*)(ws + 14680064);   // 4096x768 bf16 [.. 16,252,928)
  ushortt* vt_b   = (ushortt*)(ws + 18874368);   // 128x128x256 bf16 [.. 20,971,520)
  ushortt* xb     = (ushortt*)(ws + 20971520);   // [.. 22,544,384)
  ushortt* wqkv_b = (ushortt*)(ws + 22544384);   // [.. 23,429,120)
  ushortt* saow_b = (ushortt*)(ws + 23429120);   // [.. 23,724,032)
  ushortt* caw_b  = (ushortt*)(ws + 23724032);   // [.. 24,018,944)
  ushortt* ctx_b  = (ushortt*)(ws + 0);          // overlay qk_b (dead post-scores)
  float*   q2     = ws + 1572864;                // [.. 4,718,592) (qk_b dead)
  // ---- persistent smalls ----
  int*     pe     = (int*)(ws + 25171968);
  float*   pw     = ws + 25172000;
  float*   eo     = ws + 25172032;               // [.. 25,196,608)
  int*     cnt    = (int*)(ws + 25196608);
  // ---- expert phase ----
  float*   xz_x   = ws + 0;                      // [.. 6,291,456)
  float*   xz_z   = ws + 6291456;                // [.. 12,582,912) live -> lnfin
  ushortt* ew_b   = (ushortt*)(ws + 12582912);   // [.. 17,301,504) (scores+ctxa dead)
  float*   xc     = ws + 12582912;               // [.. 18,874,368) after ew_b dead
  float*   yac    = ws + 18874368;               // [.. 25,165,824)
  float*   dblm   = ws + 0;                      // 32x6144 [.. 196,608) xz_x dead post-conv

  // 0. fused upfront casts
  mk_mcast4<<<5952, 256, 0, stream>>>(x, xb, sa_in_w, wqkv_b, sa_out_w, saow_b,
                                      ca_in_w, caw_b);
  // 1. qkv MFMA: q,k -> qk_b bf16 (ld 1536); v -> vt_b transposed bf16
  mk_mfma<<<dim3(576, 1), 256, 0, stream>>>(xb, wqkv_b, sa_in_b, qk_b,
      768, 768, 768, 1536, 1, 0, 0, 0, 0, 0, 0, 0, nullptr, 18,
      1, 1536, vt_b, 0, 1, 1);
  // 2. scores = q @ k^T  (bf16 MFMA, K=96, Z=128, fp32 out)
  mk_mfma<<<dim3(4, 128), 256, 0, stream>>>(qk_b, qk_b + 768, nullptr, scores,
      96, 1536, 1536, 256, 8, 393216, 96, 393216, 96, 524288, 65536, 0, nullptr, 2,
      0, 1 << 30, nullptr, 0, 0, 0);
  // 3. fused softmax + att@V -> ctxa bf16
  mk_attv<<<dim3(2, 128), 256, 0, stream>>>(scores, vt_b, ctxa_b);
  // 4. ctx = ctxa @ sa_out_w^T + b -> bf16 (consumes ctxa BEFORE ew cast)
  mk_mfma<<<dim3(192, 1), 256, 0, stream>>>(ctxa_b, saow_b, sa_out_b, ctx_b,
      768, 768, 768, 768, 1, 0, 0, 0, 0, 0, 0, 0, nullptr, 6,
      1, 1 << 30, nullptr, 0, 0, 0);
  // 4b. cast expert weights (scores/ctxa regions now dead)
  mk_cast<<<9216, 256, 0, stream>>>(e_in_w, ew_b, 9437184);
  // 5. q2 = ctx @ ca_in_w[:768]^T + b (fp32 out)
  mk_mfma<<<dim3(192, 1), 256, 0, stream>>>(ctx_b, caw_b, ca_in_b, q2,
      768, 768, 768, 768, 1, 0, 0, 0, 0, 0, 0, 0, nullptr, 6,
      0, 1 << 30, nullptr, 0, 0, 0);
  // 6. fused gate path (k2 in-block + gates + top-2) -> pe/pw
  mk_gates16<<<16, 256, 0, stream>>>(q2, eq, ca_in_w + 589824, ca_in_b + 768,
                                     pe, pw);
  // 7. xz = x @ e_in_w[e]^T + b (Z=32 pair mode) split -> xz_x | xz_z
  mk_mfma<<<dim3(24, 32), 256, 0, stream>>>(xb, ew_b, e_in_b, xz_x,
      768, 768, 768, 768, 1, 196608, 0, 1179648, 0, 196608, 0, 1536, pe, 12,
      0, 768, xz_z, 768, 0, 0);
  // 8. depthwise conv + SiLU (8 tok/block, hoisted weights)
  mk_conv<<<1024, 768, 0, stream>>>(xz_x, e_conv_w, e_conv_b, pe, xc);
  // 9. dbl projections + eo/cnt zero (xz_x region dead)
  mk_dbl<<<2048, 256, 0, stream>>>(xc, e_xproj, pe, dblm, eo, cnt);
  // 10. fused segmented scan
  mk_scan<<<1536, 512, 0, stream>>>(xc, dblm, e_dtw, e_dtb, e_Alog, e_D, pe, yac);
  // 11. LN + silu(z) + token mean + (last block) final combine -> out
  mk_lnfin<<<512, 256, 0, stream>>>(yac, xz_z, e_lns, e_lnb, pe, eo, pw, out, cnt);

  (void)in_sizes; (void)n_in; (void)out_size; (void)ws_size;
}